// Round 9
// baseline (718.514 us; speedup 1.0000x reference)
//
#include <hip/hip_runtime.h>
#include <math.h>

#define T1 17
#define NN 2048
#define DIN 9
#define CC 8
#define KK 5
#define QB 4                   // queries per block
#define PD 256                 // donors per pass
#define NPASS 6
#define NDCAP (PD * NPASS)     // 1536 donor slots (E[ndon]=1024, +22 sigma)
#define NQCAP 1280             // query slots
#define PDP (PD + 4)           // sdist row pad
#define XD_BYTES (T1 * NN * CC * 4)

__device__ __forceinline__ bool lexlt(float d1, int j1, float d2, int j2) {
  return d1 < d2 || (d1 == d2 && j1 < j2);
}

// ---------------------------------------------------------------------------
// prep_a (16 blocks x 128): per-row bitmask, donor ballot per 64-row group,
// passthrough output writes, per-group colmean partial sums.
__global__ __launch_bounds__(128) void prep_a(
    const float* __restrict__ x_all, const int* __restrict__ mask,
    unsigned* __restrict__ pm, unsigned long long* __restrict__ wsbal,
    float* __restrict__ wscol, float* __restrict__ out) {
  const int row = blockIdx.x * 128 + threadIdx.x;
  const int lane = threadIdx.x & 63;
  const int g = row >> 6;
  unsigned m = 0;
#pragma unroll
  for (int t = 0; t < T1; ++t)
    m |= (mask[t * NN + row] == 0 ? 1u : 0u) << t;
  pm[row] = m;
  const bool v = (m >> 16) & 1u;
  const unsigned long long bal = __ballot(v);

  float s[CC];
#pragma unroll
  for (int c = 0; c < CC; ++c) s[c] = 0.f;
  if (v) {
    const float* r = x_all + ((size_t)16 * NN + row) * DIN;
#pragma unroll
    for (int c = 0; c < CC; ++c) {
      const float vv = r[c];
      s[c] = vv;
      out[row * CC + c] = vv;
    }
  }
#pragma unroll
  for (int off = 32; off > 0; off >>= 1) {
#pragma unroll
    for (int c = 0; c < CC; ++c) s[c] += __shfl_down(s[c], off);
  }
  if (lane == 0) {
    wsbal[g] = bal;
#pragma unroll
    for (int c = 0; c < CC; ++c) wscol[g * CC + c] = s[c];
  }
}

// ---------------------------------------------------------------------------
// prep_b (1 block x 1024): prefix over 32 group counts, ordered scatter of
// donors/queries, colmean finalize.
__global__ __launch_bounds__(1024) void prep_b(
    const unsigned* __restrict__ pm, const unsigned long long* __restrict__ wsbal,
    const float* __restrict__ wscol, int* __restrict__ dlist,
    unsigned* __restrict__ pmd, int* __restrict__ qlist,
    float* __restrict__ colmean, int* __restrict__ cnts) {
  __shared__ int dpre[33], qpre[33];
  __shared__ unsigned long long sbal[32];
  const int tid = threadIdx.x;
  if (tid < 32) sbal[tid] = wsbal[tid];
  __syncthreads();
  if (tid == 0) {
    int a = 0, b = 0;
    for (int g = 0; g < 32; ++g) {
      dpre[g] = a;
      qpre[g] = b;
      const int p = (int)__popcll(sbal[g]);
      a += p;
      b += 64 - p;
    }
    dpre[32] = a;
    qpre[32] = b;
    cnts[0] = a;  // ndon
    cnts[1] = b;  // nq
  }
  __syncthreads();
#pragma unroll
  for (int h = 0; h < 2; ++h) {
    const int row = tid + h * 1024;
    const unsigned m = pm[row];
    const int g = row >> 6, l = row & 63;
    const unsigned long long bal = sbal[g];
    const unsigned long long ltm = (1ull << l) - 1ull;
    if ((m >> 16) & 1u) {
      const int p = dpre[g] + (int)__popcll(bal & ltm);
      dlist[p] = row;
      pmd[p] = m;
    } else {
      const int p = qpre[g] + (int)__popcll((~bal) & ltm);
      qlist[p] = row;
    }
  }
  if (tid < CC) {
    float tot = 0.f;
#pragma unroll
    for (int g = 0; g < 32; ++g) tot += wscol[g * CC + tid];
    colmean[tid] = tot / fmaxf((float)dpre[32], 1.f);
  }
}

// ---------------------------------------------------------------------------
// Pack donor data t-major: xd[t][dn][c] = x_all[t][dlist[dn]][c]
__global__ void transpose_kernel(const float* __restrict__ x_all,
                                 const int* __restrict__ dlist,
                                 const int* __restrict__ cnts,
                                 float* __restrict__ xd) {
  const int u = blockIdx.x * 256 + threadIdx.x;
  if (u >= T1 * NN * CC) return;
  const int t = u / (NN * CC);
  const int rem = u % (NN * CC);
  const int dn = rem >> 3;
  const int c = rem & 7;
  if (dn < cnts[0]) xd[u] = x_all[((size_t)t * NN + dlist[dn]) * DIN + c];
}

// ---------------------------------------------------------------------------
// Main: one block (512 thr) per FOUR query rows. Thread (qd,dg) holds one
// donor's float4 in regs per t (coalesced 1KB/wave) and loops 4 queries in
// regs; query vecs via LDS broadcast reads. 6 passes of 256 donors; per-pass
// selection (wave w = channel w, 4 queries sequential) merges into running
// top-5 held UNIFORM (readfirstlane -> SGPR). Tie-exact vs numpy top_k.
__global__ __launch_bounds__(512, 6) void knn_main(
    const float* __restrict__ x_all, const float* __restrict__ xd,
    const unsigned* __restrict__ pm, const unsigned* __restrict__ pmd,
    const int* __restrict__ qlist, const int* __restrict__ cnts,
    const float* __restrict__ colmean, float* __restrict__ out) {
  __shared__ float sdist[QB][CC][PDP];  // 33,280 B
  __shared__ float qlds[QB][16][CC];    // 2 KB
  __shared__ float rcp17[32];
  const int nq = cnts[1];
  const int ndon = cnts[0];
  const int tid = threadIdx.x;
  const int bid = blockIdx.x;
  if (bid * QB >= nq) return;

  // block-uniform query masks (SGPR)
  unsigned mi0, mi1, mi2, mi3;
  {
    const int q0 = bid * QB;
    const int i0 = qlist[q0];
    const int i1 = (q0 + 1 < nq) ? qlist[q0 + 1] : -1;
    const int i2 = (q0 + 2 < nq) ? qlist[q0 + 2] : -1;
    const int i3 = (q0 + 3 < nq) ? qlist[q0 + 3] : -1;
    mi0 = (unsigned)__builtin_amdgcn_readfirstlane((int)pm[i0]);
    mi1 = (unsigned)__builtin_amdgcn_readfirstlane((int)(i1 >= 0 ? pm[i1] : 0u));
    mi2 = (unsigned)__builtin_amdgcn_readfirstlane((int)(i2 >= 0 ? pm[i2] : 0u));
    mi3 = (unsigned)__builtin_amdgcn_readfirstlane((int)(i3 >= 0 ? pm[i3] : 0u));
  }

  if (tid < 32) rcp17[tid] = 17.f / (float)tid;  // [0] = inf, guarded
  {
    const int q = tid >> 7, r = tid & 127, t = r >> 3, c = r & 7;
    const int qq = bid * QB + q;
    const int i2 = (qq < nq) ? qlist[qq] : qlist[bid * QB];
    qlds[q][t][c] = x_all[((size_t)t * NN + i2) * DIN + c];
  }
  __syncthreads();

  const int qd = tid & 1;   // channel half
  const int c0 = qd * 4;
  const int dg = tid >> 1;  // donor within pass [0,256)
  const int lane = tid & 63;
  const int w = tid >> 6;   // wave id = channel

  // running top-5 per query, uniform values (SGPR-friendly)
  float rd[QB][KK];
  int rj[QB][KK];
#pragma unroll
  for (int q = 0; q < QB; ++q)
#pragma unroll
    for (int k = 0; k < KK; ++k) { rd[q][k] = INFINITY; rj[q][k] = 0x7FFFFFFF; }

  for (int p = 0; p < NPASS; ++p) {
    const int pbase = p * PD;
    if (pbase >= ndon) break;  // block-uniform
    const int dn = pbase + dg;
    unsigned mk[QB];
    const unsigned pmdv = (dn < ndon) ? pmd[dn] : 0u;
    mk[0] = mi0 & pmdv;
    mk[1] = mi1 & pmdv;
    mk[2] = mi2 & pmdv;
    mk[3] = mi3 & pmdv;
    float ac[QB][4];
#pragma unroll
    for (int q = 0; q < QB; ++q) { ac[q][0] = ac[q][1] = ac[q][2] = ac[q][3] = 0.f; }

    const float* dvp = xd + (size_t)dn * CC + c0;
#pragma unroll
    for (int t = 0; t < 16; ++t) {
      const float4 dv = *(const float4*)(dvp + (size_t)t * (NN * CC));
#pragma unroll
      for (int q = 0; q < QB; ++q) {
        const float4 qv = *(const float4*)&qlds[q][t][c0];
        const int em = ((int)(mk[q] << (31 - t))) >> 31;
        float e;
        e = qv.x - dv.x; e = __int_as_float(__float_as_int(e) & em); ac[q][0] = fmaf(e, e, ac[q][0]);
        e = qv.y - dv.y; e = __int_as_float(__float_as_int(e) & em); ac[q][1] = fmaf(e, e, ac[q][1]);
        e = qv.z - dv.z; e = __int_as_float(__float_as_int(e) & em); ac[q][2] = fmaf(e, e, ac[q][2]);
        e = qv.w - dv.w; e = __int_as_float(__float_as_int(e) & em); ac[q][3] = fmaf(e, e, ac[q][3]);
      }
    }

#pragma unroll
    for (int q = 0; q < QB; ++q) {
      const int cnt = __popc(mk[q]);
      const float sc = rcp17[cnt & 31];
      const bool ok = cnt > 0;
      sdist[q][c0 + 0][dg] = ok ? sqrtf(ac[q][0] * sc) : INFINITY;
      sdist[q][c0 + 1][dg] = ok ? sqrtf(ac[q][1] * sc) : INFINITY;
      sdist[q][c0 + 2][dg] = ok ? sqrtf(ac[q][2] * sc) : INFINITY;
      sdist[q][c0 + 3][dg] = ok ? sqrtf(ac[q][3] * sc) : INFINITY;
    }
    __syncthreads();

    // selection: wave w = channel w; queries sequential
#pragma unroll
    for (int q = 0; q < QB; ++q) {
      float d0 = sdist[q][w][lane];
      float d1 = sdist[q][w][64 + lane];
      float d2 = sdist[q][w][128 + lane];
      float d3 = sdist[q][w][192 + lane];
      for (int k = 0; k < KK; ++k) {
        float g = fminf(fminf(d0, d1), fminf(d2, d3));
#pragma unroll
        for (int off = 32; off > 0; off >>= 1) g = fminf(g, __shfl_xor(g, off));
        if (!(g < INFINITY)) break;  // uniform
        int jloc = 0x7FFFFFFF;
        if (d3 == g) jloc = 192 + lane;
        if (d2 == g) jloc = 128 + lane;
        if (d1 == g) jloc = 64 + lane;
        if (d0 == g) jloc = lane;
#pragma unroll
        for (int off = 32; off > 0; off >>= 1) jloc = min(jloc, __shfl_xor(jloc, off));
        const int jgs = __builtin_amdgcn_readfirstlane(jloc);
        const float gf = __int_as_float(__builtin_amdgcn_readfirstlane(__float_as_int(g)));
        const int ja = pbase + jgs;
        if (!lexlt(gf, ja, rd[q][KK - 1], rj[q][KK - 1])) break;  // uniform
        rd[q][KK - 1] = gf;
        rj[q][KK - 1] = ja;
#pragma unroll
        for (int s = KK - 2; s >= 0; --s) {
          if (lexlt(rd[q][s + 1], rj[q][s + 1], rd[q][s], rj[q][s])) {
            float td = rd[q][s]; rd[q][s] = rd[q][s + 1]; rd[q][s + 1] = td;
            int tj = rj[q][s]; rj[q][s] = rj[q][s + 1]; rj[q][s + 1] = tj;
          }
        }
        const int tu = jgs >> 6, tl = jgs & 63;
        if (tu == 0 && lane == tl) d0 = INFINITY;
        if (tu == 1 && lane == tl) d1 = INFINITY;
        if (tu == 2 && lane == tl) d2 = INFINITY;
        if (tu == 3 && lane == tl) d3 = INFINITY;
      }
    }
    __syncthreads();  // protect sdist before next pass overwrites
  }

  // ---- output: sum donor values in ascending (d, j) order ----
  const float* __restrict__ xd16 = xd + (size_t)16 * NN * CC;
#pragma unroll
  for (int q = 0; q < QB; ++q) {
    const int qq = bid * QB + q;
    float sum = 0.f;
    int cn = 0;
#pragma unroll
    for (int k = 0; k < KK; ++k) {
      if (rd[q][k] < INFINITY) { sum += xd16[rj[q][k] * CC + w]; ++cn; }
    }
    if (lane == 0 && qq < nq) {
      const int i = qlist[qq];
      out[i * CC + w] = (cn > 0) ? sum / (float)cn : colmean[w];
    }
  }
}

// ---------------------------------------------------------------------------
extern "C" void kernel_launch(void* const* d_in, const int* in_sizes, int n_in,
                              void* d_out, int out_size, void* d_ws, size_t ws_size,
                              hipStream_t stream) {
  const float* x_all = (const float*)d_in[0];  // [17, 2048, 9] f32
  const int* mask = (const int*)d_in[1];       // [17, 2048] i32
  float* out = (float*)d_out;                  // [2048, 8] f32

  char* ws = (char*)d_ws;
  float* xd = (float*)ws;
  unsigned* pm = (unsigned*)(ws + XD_BYTES);
  int* dlist = (int*)(ws + XD_BYTES + NN * 4);
  unsigned* pmd = (unsigned*)(ws + XD_BYTES + NN * 8);
  int* qlist = (int*)(ws + XD_BYTES + NN * 12);
  float* colmean = (float*)(ws + XD_BYTES + NN * 16);
  int* cnts = (int*)(ws + XD_BYTES + NN * 16 + CC * 4);
  unsigned long long* wsbal = (unsigned long long*)(ws + XD_BYTES + NN * 16 + CC * 4 + 64);
  float* wscol = (float*)(ws + XD_BYTES + NN * 16 + CC * 4 + 64 + 32 * 8);

  prep_a<<<16, 128, 0, stream>>>(x_all, mask, pm, wsbal, wscol, out);
  prep_b<<<1, 1024, 0, stream>>>(pm, wsbal, wscol, dlist, pmd, qlist, colmean, cnts);
  transpose_kernel<<<(T1 * NN * CC + 255) / 256, 256, 0, stream>>>(x_all, dlist, cnts, xd);
  knn_main<<<NQCAP / QB, 512, 0, stream>>>(x_all, xd, pm, pmd, qlist, cnts, colmean, out);
}

// Round 10
// 58.891 us; speedup vs baseline: 12.2008x; 12.2008x over previous
//
#include <hip/hip_runtime.h>
#include <math.h>

#define T1 17
#define NN 2048
#define DIN 9
#define CC 8
#define KK 5
#define QB 2                   // queries per block
#define NSTR 3                 // donor streams per thread
#define PDON (NSTR * 256)      // 768 donors per pass
#define NPASS 2
#define NDCAP (PDON * NPASS)   // 1536 donor slots (E[ndon]=1024, +22 sigma)
#define NQCAP 1280
#define SPAD (PDON + 8)        // 776
#define NUP (PDON / 64)        // 12 cached distances per lane per pass
#define XD_BYTES (T1 * NN * CC * 4)

__device__ __forceinline__ bool lexlt(float d1, int j1, float d2, int j2) {
  return d1 < d2 || (d1 == d2 && j1 < j2);
}

// ---------------------------------------------------------------------------
__global__ __launch_bounds__(128) void prep_a(
    const float* __restrict__ x_all, const int* __restrict__ mask,
    unsigned* __restrict__ pm, unsigned long long* __restrict__ wsbal,
    float* __restrict__ wscol, float* __restrict__ out) {
  const int row = blockIdx.x * 128 + threadIdx.x;
  const int lane = threadIdx.x & 63;
  const int g = row >> 6;
  unsigned m = 0;
#pragma unroll
  for (int t = 0; t < T1; ++t)
    m |= (mask[t * NN + row] == 0 ? 1u : 0u) << t;
  pm[row] = m;
  const bool v = (m >> 16) & 1u;
  const unsigned long long bal = __ballot(v);

  float s[CC];
#pragma unroll
  for (int c = 0; c < CC; ++c) s[c] = 0.f;
  if (v) {
    const float* r = x_all + ((size_t)16 * NN + row) * DIN;
#pragma unroll
    for (int c = 0; c < CC; ++c) {
      const float vv = r[c];
      s[c] = vv;
      out[row * CC + c] = vv;
    }
  }
#pragma unroll
  for (int off = 32; off > 0; off >>= 1) {
#pragma unroll
    for (int c = 0; c < CC; ++c) s[c] += __shfl_down(s[c], off);
  }
  if (lane == 0) {
    wsbal[g] = bal;
#pragma unroll
    for (int c = 0; c < CC; ++c) wscol[g * CC + c] = s[c];
  }
}

// ---------------------------------------------------------------------------
__global__ __launch_bounds__(1024) void prep_b(
    const unsigned* __restrict__ pm, const unsigned long long* __restrict__ wsbal,
    const float* __restrict__ wscol, int* __restrict__ dlist,
    unsigned* __restrict__ pmd, int* __restrict__ qlist,
    float* __restrict__ colmean, int* __restrict__ cnts) {
  __shared__ int dpre[33], qpre[33];
  __shared__ unsigned long long sbal[32];
  const int tid = threadIdx.x;
  if (tid < 32) sbal[tid] = wsbal[tid];
  __syncthreads();
  if (tid == 0) {
    int a = 0, b = 0;
    for (int g = 0; g < 32; ++g) {
      dpre[g] = a;
      qpre[g] = b;
      const int p = (int)__popcll(sbal[g]);
      a += p;
      b += 64 - p;
    }
    dpre[32] = a;
    qpre[32] = b;
    cnts[0] = a;  // ndon
    cnts[1] = b;  // nq
  }
  __syncthreads();
#pragma unroll
  for (int h = 0; h < 2; ++h) {
    const int row = tid + h * 1024;
    const unsigned m = pm[row];
    const int g = row >> 6, l = row & 63;
    const unsigned long long bal = sbal[g];
    const unsigned long long ltm = (1ull << l) - 1ull;
    if ((m >> 16) & 1u) {
      const int p = dpre[g] + (int)__popcll(bal & ltm);
      dlist[p] = row;
      pmd[p] = m;
    } else {
      const int p = qpre[g] + (int)__popcll((~bal) & ltm);
      qlist[p] = row;
    }
  }
  if (tid < CC) {
    float tot = 0.f;
#pragma unroll
    for (int g = 0; g < 32; ++g) tot += wscol[g * CC + tid];
    colmean[tid] = tot / fmaxf((float)dpre[32], 1.f);
  }
}

// ---------------------------------------------------------------------------
// Pack donor data t-major: xd[t][dn][c] = x_all[t][dlist[dn]][c]
__global__ void transpose_kernel(const float* __restrict__ x_all,
                                 const int* __restrict__ dlist,
                                 const int* __restrict__ cnts,
                                 float* __restrict__ xd) {
  const int u = blockIdx.x * 256 + threadIdx.x;
  if (u >= T1 * NN * CC) return;
  const int t = u / (NN * CC);
  const int rem = u % (NN * CC);
  const int dn = rem >> 3;
  const int c = rem & 7;
  if (dn < cnts[0]) xd[u] = x_all[((size_t)t * NN + dlist[dn]) * DIN + c];
}

// ---------------------------------------------------------------------------
#define ACC4(QV, DV, EM, A0, A1, A2, A3)                          \
  {                                                               \
    float e;                                                      \
    e = QV.x - DV.x; e = __int_as_float(__float_as_int(e) & EM); A0 = fmaf(e, e, A0); \
    e = QV.y - DV.y; e = __int_as_float(__float_as_int(e) & EM); A1 = fmaf(e, e, A1); \
    e = QV.z - DV.z; e = __int_as_float(__float_as_int(e) & EM); A2 = fmaf(e, e, A2); \
    e = QV.w - DV.w; e = __int_as_float(__float_as_int(e) & EM); A3 = fmaf(e, e, A3); \
  }

#define SQW(Q, S, MK, A0, A1, A2, A3)                                       \
  {                                                                         \
    const int cnt = __popc(MK);                                             \
    const float sc = rcp17[cnt & 31];                                       \
    const bool ok = cnt > 0;                                                \
    sdist[Q][c0 + 0][dg + 256 * S] = ok ? sqrtf(A0 * sc) : INFINITY;        \
    sdist[Q][c0 + 1][dg + 256 * S] = ok ? sqrtf(A1 * sc) : INFINITY;        \
    sdist[Q][c0 + 2][dg + 256 * S] = ok ? sqrtf(A2 * sc) : INFINITY;        \
    sdist[Q][c0 + 3][dg + 256 * S] = ok ? sqrtf(A3 * sc) : INFINITY;        \
  }

// Per-pass 5-round extraction merging into NAMED running top-5 (all static
// indexing -> registers; proven logic from R7).
#define EXTRACT5(Q, RD0, RD1, RD2, RD3, RD4, RJ0, RJ1, RJ2, RJ3, RJ4)       \
  do {                                                                      \
    float dvr[NUP];                                                         \
    _Pragma("unroll")                                                       \
    for (int u = 0; u < NUP; ++u) dvr[u] = sdist[Q][w][u * 64 + lane];      \
    for (int k = 0; k < KK; ++k) {                                          \
      float g = dvr[0];                                                     \
      _Pragma("unroll")                                                     \
      for (int u = 1; u < NUP; ++u) g = fminf(g, dvr[u]);                   \
      _Pragma("unroll")                                                     \
      for (int off = 32; off > 0; off >>= 1) g = fminf(g, __shfl_xor(g, off)); \
      if (!(g < INFINITY)) break;                                           \
      int jloc = 0x7FFFFFFF;                                                \
      _Pragma("unroll")                                                     \
      for (int u = NUP - 1; u >= 0; --u)                                    \
        if (dvr[u] == g) jloc = u * 64 + lane;                              \
      _Pragma("unroll")                                                     \
      for (int off = 32; off > 0; off >>= 1) jloc = min(jloc, __shfl_xor(jloc, off)); \
      const int jgs = __builtin_amdgcn_readfirstlane(jloc);                 \
      const float gf = __int_as_float(__builtin_amdgcn_readfirstlane(__float_as_int(g))); \
      const int ja = pbase + jgs;                                           \
      if (!lexlt(gf, ja, RD4, RJ4)) break;                                  \
      RD4 = gf; RJ4 = ja;                                                   \
      if (lexlt(RD4, RJ4, RD3, RJ3)) { float td = RD3; RD3 = RD4; RD4 = td; int tj = RJ3; RJ3 = RJ4; RJ4 = tj; } \
      if (lexlt(RD3, RJ3, RD2, RJ2)) { float td = RD2; RD2 = RD3; RD3 = td; int tj = RJ2; RJ2 = RJ3; RJ3 = tj; } \
      if (lexlt(RD2, RJ2, RD1, RJ1)) { float td = RD1; RD1 = RD2; RD2 = td; int tj = RJ1; RJ1 = RJ2; RJ2 = tj; } \
      if (lexlt(RD1, RJ1, RD0, RJ0)) { float td = RD0; RD0 = RD1; RD1 = td; int tj = RJ0; RJ0 = RJ1; RJ1 = tj; } \
      const int tu = jgs >> 6, tl = jgs & 63;                               \
      _Pragma("unroll")                                                     \
      for (int u = 0; u < NUP; ++u)                                         \
        if (u == tu) dvr[u] = (lane == tl) ? INFINITY : dvr[u];             \
    }                                                                       \
  } while (0)

// Main: one block (512 thr) per TWO query rows. Union-mask SGPR sparse
// t-walk; 3 donor float4 streams shared by both queries (halves L2 traffic
// per pair); exec-guard skips dead-slot loads. Selection per pass per query
// with named running top-5 (tie-exact vs numpy top_k).
__global__ __launch_bounds__(512) void knn_main(
    const float* __restrict__ x_all, const float* __restrict__ xd,
    const unsigned* __restrict__ pm, const unsigned* __restrict__ pmd,
    const int* __restrict__ qlist, const int* __restrict__ cnts,
    const float* __restrict__ colmean, float* __restrict__ out) {
  __shared__ float sdist[QB][CC][SPAD];  // 49,664 B
  __shared__ float qlds[QB][16][CC];
  __shared__ float rcp17[32];
  const int nq = cnts[1];
  const int bid = blockIdx.x;
  if (bid * QB >= nq) return;
  const int ndon = cnts[0];
  const int tid = threadIdx.x;

  const int iA = qlist[bid * QB];
  const int iB = (bid * QB + 1 < nq) ? qlist[bid * QB + 1] : -1;
  const unsigned mi0 = (unsigned)__builtin_amdgcn_readfirstlane((int)pm[iA]);
  const unsigned mi1 = (unsigned)__builtin_amdgcn_readfirstlane((int)(iB >= 0 ? pm[iB] : 0u));

  if (tid < 32) rcp17[tid] = 17.f / (float)tid;  // [0]=inf, guarded by ok
  if (tid < 2 * 16 * CC) {
    const int q = tid >> 7, r = tid & 127, t = r >> 3, c = r & 7;
    const int iq = (q == 0) ? iA : (iB >= 0 ? iB : iA);
    qlds[q][t][c] = x_all[((size_t)t * NN + iq) * DIN + c];
  }
  __syncthreads();

  const int qd = tid & 1;
  const int c0 = qd * 4;
  const int dg = tid >> 1;  // [0,256)
  const int lane = tid & 63;
  const int w = tid >> 6;   // wave = channel

  // named running top-5 per query (lex ascending (d,j)), uniform values
  float rA0 = INFINITY, rA1 = INFINITY, rA2 = INFINITY, rA3 = INFINITY, rA4 = INFINITY;
  int jA0 = 0x7FFFFFFF, jA1 = 0x7FFFFFFF, jA2 = 0x7FFFFFFF, jA3 = 0x7FFFFFFF, jA4 = 0x7FFFFFFF;
  float rB0 = INFINITY, rB1 = INFINITY, rB2 = INFINITY, rB3 = INFINITY, rB4 = INFINITY;
  int jB0 = 0x7FFFFFFF, jB1 = 0x7FFFFFFF, jB2 = 0x7FFFFFFF, jB3 = 0x7FFFFFFF, jB4 = 0x7FFFFFFF;

  for (int p = 0; p < NPASS; ++p) {
    const int pbase = p * PDON;
    if (pbase >= ndon) break;  // block-uniform

    const int dn0 = pbase + dg, dn1 = dn0 + 256, dn2 = dn0 + 512;
    const unsigned pv0 = (dn0 < ndon) ? pmd[dn0] : 0u;
    const unsigned pv1 = (dn1 < ndon) ? pmd[dn1] : 0u;
    const unsigned pv2 = (dn2 < ndon) ? pmd[dn2] : 0u;
    const unsigned mA0 = mi0 & pv0, mB0 = mi1 & pv0;
    const unsigned mA1 = mi0 & pv1, mB1 = mi1 & pv1;
    const unsigned mA2 = mi0 & pv2, mB2 = mi1 & pv2;
    const int off0 = dn0 * CC + c0, off1 = dn1 * CC + c0, off2 = dn2 * CC + c0;

    float aA00 = 0.f, aA01 = 0.f, aA02 = 0.f, aA03 = 0.f;
    float aA10 = 0.f, aA11 = 0.f, aA12 = 0.f, aA13 = 0.f;
    float aA20 = 0.f, aA21 = 0.f, aA22 = 0.f, aA23 = 0.f;
    float aB00 = 0.f, aB01 = 0.f, aB02 = 0.f, aB03 = 0.f;
    float aB10 = 0.f, aB11 = 0.f, aB12 = 0.f, aB13 = 0.f;
    float aB20 = 0.f, aB21 = 0.f, aB22 = 0.f, aB23 = 0.f;

    unsigned tm = (mi0 | mi1) & 0xFFFFu;  // SGPR union walk
    while (tm) {
      const int t = __ffs(tm) - 1;
      tm &= tm - 1u;
      const int shv = 31 - t;
      const float* __restrict__ pt = xd + (size_t)t * (NN * CC);
      const float4 qvA = *(const float4*)&qlds[0][t][c0];
      const float4 qvB = *(const float4*)&qlds[1][t][c0];
      if (mA0 | mB0) {
        const float4 dv = *(const float4*)(pt + off0);
        const int eA = ((int)(mA0 << shv)) >> 31;
        const int eB = ((int)(mB0 << shv)) >> 31;
        ACC4(qvA, dv, eA, aA00, aA01, aA02, aA03);
        ACC4(qvB, dv, eB, aB00, aB01, aB02, aB03);
      }
      if (mA1 | mB1) {
        const float4 dv = *(const float4*)(pt + off1);
        const int eA = ((int)(mA1 << shv)) >> 31;
        const int eB = ((int)(mB1 << shv)) >> 31;
        ACC4(qvA, dv, eA, aA10, aA11, aA12, aA13);
        ACC4(qvB, dv, eB, aB10, aB11, aB12, aB13);
      }
      if (mA2 | mB2) {
        const float4 dv = *(const float4*)(pt + off2);
        const int eA = ((int)(mA2 << shv)) >> 31;
        const int eB = ((int)(mB2 << shv)) >> 31;
        ACC4(qvA, dv, eA, aA20, aA21, aA22, aA23);
        ACC4(qvB, dv, eB, aB20, aB21, aB22, aB23);
      }
    }

    SQW(0, 0, mA0, aA00, aA01, aA02, aA03);
    SQW(0, 1, mA1, aA10, aA11, aA12, aA13);
    SQW(0, 2, mA2, aA20, aA21, aA22, aA23);
    SQW(1, 0, mB0, aB00, aB01, aB02, aB03);
    SQW(1, 1, mB1, aB10, aB11, aB12, aB13);
    SQW(1, 2, mB2, aB20, aB21, aB22, aB23);
    __syncthreads();

    EXTRACT5(0, rA0, rA1, rA2, rA3, rA4, jA0, jA1, jA2, jA3, jA4);
    EXTRACT5(1, rB0, rB1, rB2, rB3, rB4, jB0, jB1, jB2, jB3, jB4);
    __syncthreads();  // protect sdist before next pass overwrites
  }

  // ---- outputs: sum donor values in ascending (d, j) order ----
  const float* __restrict__ xd16 = xd + (size_t)16 * NN * CC;
  {
    float sum = 0.f;
    int cn = 0;
    if (rA0 < INFINITY) { sum += xd16[jA0 * CC + w]; ++cn; }
    if (rA1 < INFINITY) { sum += xd16[jA1 * CC + w]; ++cn; }
    if (rA2 < INFINITY) { sum += xd16[jA2 * CC + w]; ++cn; }
    if (rA3 < INFINITY) { sum += xd16[jA3 * CC + w]; ++cn; }
    if (rA4 < INFINITY) { sum += xd16[jA4 * CC + w]; ++cn; }
    if (lane == 0) out[iA * CC + w] = (cn > 0) ? sum / (float)cn : colmean[w];
  }
  if (iB >= 0) {
    float sum = 0.f;
    int cn = 0;
    if (rB0 < INFINITY) { sum += xd16[jB0 * CC + w]; ++cn; }
    if (rB1 < INFINITY) { sum += xd16[jB1 * CC + w]; ++cn; }
    if (rB2 < INFINITY) { sum += xd16[jB2 * CC + w]; ++cn; }
    if (rB3 < INFINITY) { sum += xd16[jB3 * CC + w]; ++cn; }
    if (rB4 < INFINITY) { sum += xd16[jB4 * CC + w]; ++cn; }
    if (lane == 0) out[iB * CC + w] = (cn > 0) ? sum / (float)cn : colmean[w];
  }
}

// ---------------------------------------------------------------------------
extern "C" void kernel_launch(void* const* d_in, const int* in_sizes, int n_in,
                              void* d_out, int out_size, void* d_ws, size_t ws_size,
                              hipStream_t stream) {
  const float* x_all = (const float*)d_in[0];  // [17, 2048, 9] f32
  const int* mask = (const int*)d_in[1];       // [17, 2048] i32
  float* out = (float*)d_out;                  // [2048, 8] f32

  char* ws = (char*)d_ws;
  float* xd = (float*)ws;
  unsigned* pm = (unsigned*)(ws + XD_BYTES);
  int* dlist = (int*)(ws + XD_BYTES + NN * 4);
  unsigned* pmd = (unsigned*)(ws + XD_BYTES + NN * 8);
  int* qlist = (int*)(ws + XD_BYTES + NN * 12);
  float* colmean = (float*)(ws + XD_BYTES + NN * 16);
  int* cnts = (int*)(ws + XD_BYTES + NN * 16 + CC * 4);
  unsigned long long* wsbal = (unsigned long long*)(ws + XD_BYTES + NN * 16 + CC * 4 + 64);
  float* wscol = (float*)(ws + XD_BYTES + NN * 16 + CC * 4 + 64 + 32 * 8);

  prep_a<<<16, 128, 0, stream>>>(x_all, mask, pm, wsbal, wscol, out);
  prep_b<<<1, 1024, 0, stream>>>(pm, wsbal, wscol, dlist, pmd, qlist, colmean, cnts);
  transpose_kernel<<<(T1 * NN * CC + 255) / 256, 256, 0, stream>>>(x_all, dlist, cnts, xd);
  knn_main<<<NQCAP / QB, 512, 0, stream>>>(x_all, xd, pm, pmd, qlist, cnts, colmean, out);
}